// Round 7
// baseline (1379.613 us; speedup 1.0000x reference)
//
#include <hip/hip_runtime.h>
#include <math.h>

#define S_LEN 100
#define NCAT  18
#define HS    516   // hstage row stride in shorts (2-way bank aliasing = free)

typedef __attribute__((ext_vector_type(8)))  short  short8;
typedef __attribute__((ext_vector_type(16))) float  floatx16;

#define AT_LOADU(p)   __hip_atomic_load((p), __ATOMIC_RELAXED, __HIP_MEMORY_SCOPE_AGENT)
#define AT_STORE(p,v) __hip_atomic_store((p),(v), __ATOMIC_RELAXED, __HIP_MEMORY_SCOPE_AGENT)

// ws byte layout:
//   H0[lstm][buf]: bf16 [64 b][256 k] at (lstm*2+buf)*32768         (0..131071)
//   H1[lstm][buf]: same              at 131072 + (lstm*2+buf)*32768  (..262143)
//   flags: group g in {0,1}: 32 slots x 16 B at 262144 + g*512
// All H + flag traffic via relaxed agent-scope atomics (sc1, IF-coherent; R5/R6-proven).

struct Params {
  const int* ivu; const int* ivo;
  const float* lro; const float* lru;
  const float* VE;
  const float* W[4][2];   // [inst][part]; inst: bit0=lstm, bit1=layer; part0=Wih, part1=Whh
  const float* b0[4]; const float* b1[4];
  const float* roW; const float* rob;
  const float* ruW; const float* rub;
  float* ws; float* out;
};

__device__ __forceinline__ unsigned short f2bf(float f) {
  unsigned u = __builtin_bit_cast(unsigned, f);
  u += 0x7FFFu + ((u >> 16) & 1u);          // RNE
  return (unsigned short)(u >> 16);
}
__device__ __forceinline__ float bf2f(unsigned short h) {
  unsigned u = ((unsigned)h) << 16;
  return __builtin_bit_cast(float, u);
}
__device__ __forceinline__ short8 pack64(unsigned long long l0, unsigned long long l1) {
  union { unsigned long long u[2]; short8 s; } c;
  c.u[0] = l0; c.u[1] = l1;
  return c.s;
}
__device__ __forceinline__ unsigned long long packbf4(float4 v) {
  return (unsigned long long)f2bf(v.x)
       | ((unsigned long long)f2bf(v.y) << 16)
       | ((unsigned long long)f2bf(v.z) << 32)
       | ((unsigned long long)f2bf(v.w) << 48);
}

__global__ void init_k(unsigned* bar, float* out) {
  bar[threadIdx.x] = 0u;                    // 256 dwords = 1 KB flag area
  if (threadIdx.x == 0) out[64] = 0.f;      // KL accumulator
}

// 64 WGs x 256 thr (4 waves). WG (inst, wg) owns gate-rows r = g*16+m_local,
// R = g*256 + wg*16 + m_local, K=512. Wave (jt,bt) computes D tile [32 r x 32 b]
// with A held in VGPRs (32 x short8) and B staged in LDS each iteration.
__global__ __launch_bounds__(256, 1) void lstm_all(Params P) {
  __shared__ unsigned short hstage[64 * HS];   // 64.5 KB: x_t as bf16 [b][k0..511]
  __shared__ float gatebuf[64 * 64];           // 16 KB
  __shared__ float cst[16 * 64];               // 4 KB
  __shared__ float bias_l[64];

  const int tid  = threadIdx.x;
  const int lane = tid & 63;
  const int wave = tid >> 6;            // 0..3
  const int blk  = blockIdx.x;
  const int inst = blk >> 4;            // 0=vu-L0 1=vo-L0 2=vu-L1 3=vo-L1
  const int wg   = blk & 15;
  const int lstm = inst & 1;
  const int layer = inst >> 1;
  const int gb   = layer * 16 + wg;     // 0..31 within lstm group

  char* wsb = (char*)P.ws;
  unsigned* arr = (unsigned*)(wsb + 262144) + lstm * 128;   // 32 slots x 4 dwords

  const int jt = wave >> 1, bt = wave & 1;
  const int half = lane >> 5;
  const int bl   = bt * 32 + (lane & 31);

  // ---- A fragments -> VGPRs (one time). rloc = jt*32 + (lane&31) in 0..63 ----
  short8 afrag[32];
  {
    const int rloc = jt * 32 + (lane & 31);
    const int R = (rloc >> 4) * 256 + wg * 16 + (rloc & 15);
    const float* wih = P.W[inst][0] + (size_t)R * 256;
    const float* whh = P.W[inst][1] + (size_t)R * 256 - 256;  // +k valid for k>=256
    #pragma unroll
    for (int s = 0; s < 32; ++s) {
      const int k0 = s * 16 + half * 8;
      const float* src = (k0 < 256 ? wih : whh) + k0;
      float4 v0 = *(const float4*)src;
      float4 v1 = *(const float4*)(src + 4);
      short8 a;
      a[0] = (short)f2bf(v0.x); a[1] = (short)f2bf(v0.y);
      a[2] = (short)f2bf(v0.z); a[3] = (short)f2bf(v0.w);
      a[4] = (short)f2bf(v1.x); a[5] = (short)f2bf(v1.y);
      a[6] = (short)f2bf(v1.z); a[7] = (short)f2bf(v1.w);
      afrag[s] = a;
    }
  }
  if (tid < 64) {
    const int R = (tid >> 4) * 256 + wg * 16 + (tid & 15);
    bias_l[tid] = P.b0[inst][R] + P.b1[inst][R];
  }
  for (int i = tid; i < 16 * 64; i += 256) cst[i] = 0.f;

  // ---- zero own group's H buffers: 128 KB over 32 WGs = 2 u64 per thread ----
  #pragma unroll
  for (int j = 0; j < 2; ++j) {
    const int gi = gb * 512 + tid * 2 + j;      // 0..16383 u64 within group
    const int r = gi >> 12, off = gi & 4095;
    char* base = wsb + ((r < 2) ? (size_t)(lstm * 2 + r) * 32768
                                : 131072 + (size_t)(lstm * 2 + r - 2) * 32768);
    AT_STORE((unsigned long long*)base + off, 0ull);
  }
  __syncthreads();                       // vmcnt(0) drain: zeros IF-visible
  if (tid == 0) AT_STORE(arr + gb * 4, 1u);

  const int* __restrict__ idxp = lstm ? P.ivo : P.ivu;
  const unsigned long long* hrow = (const unsigned long long*)&hstage[bl * HS];

  for (int t = 0; t <= S_LEN; ++t) {
    // ---- one-hop barrier: wave 0 polls all 32 group slots for epoch >= t+1 ----
    if (wave == 0) {
      const unsigned want = (unsigned)(t + 1);
      const unsigned* slot = arr + (lane & 31) * 4;
      while (!__all(AT_LOADU(slot) >= want)) { }
    }
    __syncthreads();

    const bool active = (layer == 0) ? (t < S_LEN) : (t >= 1);
    if (active) {
      const int cur = t & 1, prv = (t + 1) & 1;

      // ---- stage x_t into LDS [b][516] bf16 ----
      if (layer == 0) {
        // low half: embedding gather (read-only, normally cached)
        const int b = tid >> 2, q = tid & 3;
        const int row = idxp[b * S_LEN + t];
        const float* __restrict__ vr = P.VE + (size_t)row * 256 + q * 64;
        unsigned long long* drow = (unsigned long long*)&hstage[b * HS + q * 64];
        #pragma unroll
        for (int jj = 0; jj < 16; ++jj)
          drow[jj] = packbf4(*(const float4*)(vr + jj * 4));
        // high half: h0_{t-1}
        const unsigned long long* s64 =
            (const unsigned long long*)(wsb + (size_t)(lstm * 2 + prv) * 32768);
        #pragma unroll
        for (int j = 0; j < 16; ++j) {
          const int i = tid + j * 256, bb = i >> 6, kq = i & 63;
          *(unsigned long long*)&hstage[bb * HS + 256 + kq * 4] = AT_LOADU(s64 + i);
        }
      } else {
        const unsigned long long* lo =
            (const unsigned long long*)(wsb + (size_t)(lstm * 2 + prv) * 32768);   // y0_{t-1}
        const unsigned long long* hi =
            (const unsigned long long*)(wsb + 131072 + (size_t)(lstm * 2 + cur) * 32768); // h1_{t-2}
        #pragma unroll
        for (int j = 0; j < 16; ++j) {
          const int i = tid + j * 256, bb = i >> 6, kq = i & 63;
          *(unsigned long long*)&hstage[bb * HS + kq * 4] = AT_LOADU(lo + i);
        }
        #pragma unroll
        for (int j = 0; j < 16; ++j) {
          const int i = tid + j * 256, bb = i >> 6, kq = i & 63;
          *(unsigned long long*)&hstage[bb * HS + 256 + kq * 4] = AT_LOADU(hi + i);
        }
      }
      __syncthreads();

      // ---- MFMA chain: 32 x mfma_f32_32x32x16_bf16, B from LDS ----
      floatx16 acc;
      #pragma unroll
      for (int r = 0; r < 16; ++r) acc[r] = 0.f;
      #pragma unroll
      for (int s = 0; s < 32; ++s) {
        unsigned long long l0 = hrow[s * 4 + half * 2];
        unsigned long long l1 = hrow[s * 4 + half * 2 + 1];
        acc = __builtin_amdgcn_mfma_f32_32x32x16_bf16(afrag[s], pack64(l0, l1), acc, 0, 0, 0);
      }
      #pragma unroll
      for (int r = 0; r < 16; ++r) {
        const int row = (r & 3) + 8 * (r >> 2) + 4 * half;   // C/D layout (m74/m101)
        gatebuf[(jt * 32 + row) * 64 + bl] = acc[r];
      }
      __syncthreads();

      // ---- activations: thread = (b, mq), 4 m each ----
      {
        const int b = tid & 63, mq = tid >> 6;
        unsigned long long hpack = 0ull;
        #pragma unroll
        for (int i = 0; i < 4; ++i) {
          const int m = mq * 4 + i;
          const float g0 = gatebuf[(0 * 16 + m) * 64 + b] + bias_l[0 * 16 + m];
          const float g1 = gatebuf[(1 * 16 + m) * 64 + b] + bias_l[1 * 16 + m];
          const float g2 = gatebuf[(2 * 16 + m) * 64 + b] + bias_l[2 * 16 + m];
          const float g3 = gatebuf[(3 * 16 + m) * 64 + b] + bias_l[3 * 16 + m];
          const float ig = 1.f / (1.f + __expf(-g0));
          const float fg = 1.f / (1.f + __expf(-g1));
          const float gg = tanhf(g2);
          const float og = 1.f / (1.f + __expf(-g3));
          const float c  = fg * cst[m * 64 + b] + ig * gg;
          cst[m * 64 + b] = c;
          hpack |= ((unsigned long long)f2bf(og * tanhf(c))) << (16 * i);
        }
        unsigned long long* hout = (layer == 0)
            ? (unsigned long long*)(wsb + (size_t)(lstm * 2 + cur) * 32768)
            : (unsigned long long*)(wsb + 131072 + (size_t)(lstm * 2 + prv) * 32768);
        AT_STORE(hout + b * 64 + wg * 4 + mq, hpack);
      }
    }
    if (t < S_LEN) {
      __syncthreads();                   // vmcnt(0) drain: h stores IF-visible
      if (tid == 0) AT_STORE(arr + gb * 4, (unsigned)(t + 2));
    }
  }
}

// head: 64 blocks (one per batch) x 64 threads
__global__ __launch_bounds__(64) void head_kernel(Params P) {
  __shared__ float enc[256];
  __shared__ float dec[NCAT];
  const int b = blockIdx.x, t = threadIdx.x;
  char* wsb = (char*)P.ws;
  const unsigned short* hvu = (const unsigned short*)(wsb + 131072 + 1 * 32768) + b * 256;
  const unsigned short* hvo = (const unsigned short*)(wsb + 131072 + 3 * 32768) + b * 256;

  for (int m = t; m < 256; m += 64) {
    float s = P.rob[m];
    for (int j = 0; j < NCAT; ++j) s = fmaf(P.lro[b * NCAT + j], P.roW[m * NCAT + j], s);
    enc[m] = fmaxf(s, 0.f);
  }
  __syncthreads();
  for (int n = 0; n < NCAT; ++n) {
    const float* __restrict__ wr = P.ruW + n * 768;
    float s = 0.f;
    for (int k = t; k < 256; k += 64) {
      s = fmaf(bf2f(hvu[k]), wr[k], s);
      s = fmaf(bf2f(hvo[k]), wr[256 + k], s);
      s = fmaf(enc[k],       wr[512 + k], s);
    }
    for (int off = 32; off; off >>= 1) s += __shfl_down(s, off, 64);
    if (t == 0) dec[n] = s + P.rub[n];
  }
  __syncthreads();
  if (t == 0) {
    float M = dec[0];
    for (int j = 1; j < NCAT; ++j) M = fmaxf(M, dec[j]);
    float Ssum = 0.f;
    for (int j = 0; j < NCAT; ++j) Ssum += expf(dec[j] - M);
    const float lse = M + logf(Ssum);
    float neg = 0.f, kl = 0.f;
    for (int j = 0; j < NCAT; ++j) {
      const float lp = dec[j] - lse;
      const float q  = P.lru[b * NCAT + j];
      neg -= q * lp;
      kl  += q * (logf(q) - lp);
    }
    P.out[b] = neg;
    atomicAdd(&P.out[64], kl * 1.4426950408889634f * (1.f / 64.f));
  }
}

extern "C" void kernel_launch(void* const* d_in, const int* in_sizes, int n_in,
                              void* d_out, int out_size, void* d_ws, size_t ws_size,
                              hipStream_t stream) {
  Params P;
  P.ivu = (const int*)d_in[0];
  P.ivo = (const int*)d_in[1];
  P.lro = (const float*)d_in[2];
  if (in_sizes[3] >= in_sizes[4]) { P.VE = (const float*)d_in[3]; P.lru = (const float*)d_in[4]; }
  else                            { P.VE = (const float*)d_in[4]; P.lru = (const float*)d_in[3]; }
  // inst: 0 = vu-L0, 1 = vo-L0, 2 = vu-L1, 3 = vo-L1
  P.W[0][0] = (const float*)d_in[5];  P.W[0][1] = (const float*)d_in[6];
  P.b0[0]   = (const float*)d_in[7];  P.b1[0]   = (const float*)d_in[8];
  P.W[2][0] = (const float*)d_in[9];  P.W[2][1] = (const float*)d_in[10];
  P.b0[2]   = (const float*)d_in[11]; P.b1[2]   = (const float*)d_in[12];
  P.W[1][0] = (const float*)d_in[13]; P.W[1][1] = (const float*)d_in[14];
  P.b0[1]   = (const float*)d_in[15]; P.b1[1]   = (const float*)d_in[16];
  P.W[3][0] = (const float*)d_in[17]; P.W[3][1] = (const float*)d_in[18];
  P.b0[3]   = (const float*)d_in[19]; P.b1[3]   = (const float*)d_in[20];
  P.roW = (const float*)d_in[21]; P.rob = (const float*)d_in[22];
  P.ruW = (const float*)d_in[23]; P.rub = (const float*)d_in[24];
  P.ws  = (float*)d_ws;
  P.out = (float*)d_out;

  unsigned* bar = (unsigned*)((char*)d_ws + 262144);
  init_k<<<1, 256, 0, stream>>>(bar, P.out);

  void* args[] = { &P };
  hipLaunchCooperativeKernel((void*)lstm_all, dim3(64), dim3(256), args, 0, stream);
  head_kernel<<<64, 64, 0, stream>>>(P);
}

// Round 8
// 989.031 us; speedup vs baseline: 1.3949x; 1.3949x over previous
//
#include <hip/hip_runtime.h>
#include <math.h>

#define S_LEN 100
#define NCAT  18
#define HS    516   // hstage row stride in shorts
#define WSTR  520   // Wlds row stride in shorts

typedef __attribute__((ext_vector_type(8)))  short  short8;
typedef __attribute__((ext_vector_type(16))) float  floatx16;

#define AT_LOADU(p)   __hip_atomic_load((p), __ATOMIC_RELAXED, __HIP_MEMORY_SCOPE_AGENT)
#define AT_STORE(p,v) __hip_atomic_store((p),(v), __ATOMIC_RELAXED, __HIP_MEMORY_SCOPE_AGENT)

// ws byte layout:
//   H0[lstm][buf]: bf16 [64 b][256 k] at (lstm*2+buf)*32768         (0..131071)
//   H1[lstm][buf]: same              at 131072 + (lstm*2+buf)*32768  (..262143)
//   flags: group g in {0,1}: 32 slots x 16 B at 262144 + g*512
// All H + flag traffic via relaxed agent-scope atomics (sc1, IF-coherent).

struct Params {
  const int* ivu; const int* ivo;
  const float* lro; const float* lru;
  const float* VE;
  const float* W[4][2];
  const float* b0[4]; const float* b1[4];
  const float* roW; const float* rob;
  const float* ruW; const float* rub;
  float* ws; float* out;
};

__device__ __forceinline__ unsigned short f2bf(float f) {
  unsigned u = __builtin_bit_cast(unsigned, f);
  u += 0x7FFFu + ((u >> 16) & 1u);          // RNE
  return (unsigned short)(u >> 16);
}
__device__ __forceinline__ float bf2f(unsigned short h) {
  unsigned u = ((unsigned)h) << 16;
  return __builtin_bit_cast(float, u);
}
__device__ __forceinline__ unsigned long long packbf4(float4 v) {
  return (unsigned long long)f2bf(v.x)
       | ((unsigned long long)f2bf(v.y) << 16)
       | ((unsigned long long)f2bf(v.z) << 32)
       | ((unsigned long long)f2bf(v.w) << 48);
}

__global__ void init_k(unsigned* bar, float* out) {
  bar[threadIdx.x] = 0u;                    // 256 dwords
  if (threadIdx.x == 0) out[64] = 0.f;      // KL accumulator
}

// 64 WGs x 256 thr (4 waves). WG (inst, wg) owns gate-rows r = g*16+m_local,
// R = g*256 + wg*16 + m_local, K=512. Wave (jt,bt) computes D tile [32 r x 32 b]
// with A in LDS (Wlds, staged once) and B staged to LDS (hstage) each iter via
// explicit deep load batches (low VGPR pressure => all loads in flight).
__global__ __launch_bounds__(256, 1) void lstm_all(Params P) {
  __shared__ short          Wlds[64 * WSTR];    // 66.5 KB bf16 weights
  __shared__ unsigned short hstage[64 * HS];    // 64.5 KB x_t bf16 [b][k]
  __shared__ float          gatebuf[64 * 64];   // 16 KB
  __shared__ float          cst[16 * 64];       // 4 KB
  __shared__ float          bias_l[64];

  const int tid  = threadIdx.x;
  const int lane = tid & 63;
  const int wave = tid >> 6;            // 0..3
  const int blk  = blockIdx.x;
  const int inst = blk >> 4;            // 0=vu-L0 1=vo-L0 2=vu-L1 3=vo-L1
  const int wg   = blk & 15;
  const int lstm = inst & 1;
  const int layer = inst >> 1;
  const int gb   = layer * 16 + wg;     // 0..31 within lstm group

  char* wsb = (char*)P.ws;
  unsigned* arr = (unsigned*)(wsb + 262144) + lstm * 128;   // 32 slots x 4 dwords

  const int jt = wave >> 1, bt = wave & 1;
  const int half = lane >> 5;
  const int bl   = bt * 32 + (lane & 31);

  // ---- stage weights -> LDS bf16 (one time; reread 101x) ----
  {
    const int jrow = tid >> 2;          // 0..63 = g*16+m
    const int q    = tid & 3;
    const int R    = (jrow >> 4) * 256 + wg * 16 + (jrow & 15);
    const float* wih = P.W[inst][0] + (size_t)R * 256;
    const float* whh = P.W[inst][1] + (size_t)R * 256;
    short* dst = &Wlds[jrow * WSTR];
    #pragma unroll
    for (int k = q * 128; k < q * 128 + 128; k += 8) {
      const float* src = (k < 256) ? (wih + k) : (whh + (k - 256));
      float4 v0 = *(const float4*)src;
      float4 v1 = *(const float4*)(src + 4);
      *(unsigned long long*)(dst + k)     = packbf4(v0);
      *(unsigned long long*)(dst + k + 4) = packbf4(v1);
    }
  }
  if (tid < 64) {
    const int R = (tid >> 4) * 256 + wg * 16 + (tid & 15);
    bias_l[tid] = P.b0[inst][R] + P.b1[inst][R];
  }
  for (int i = tid; i < 16 * 64; i += 256) cst[i] = 0.f;

  // ---- zero own group's H buffers: 128 KB over 32 WGs = 2 u64 per thread ----
  #pragma unroll
  for (int j = 0; j < 2; ++j) {
    const int gi = gb * 512 + tid * 2 + j;
    const int r = gi >> 12, off = gi & 4095;
    char* base = wsb + ((r < 2) ? (size_t)(lstm * 2 + r) * 32768
                                : 131072 + (size_t)(lstm * 2 + r - 2) * 32768);
    AT_STORE((unsigned long long*)base + off, 0ull);
  }
  __syncthreads();                       // vmcnt(0) drain
  if (tid == 0) AT_STORE(arr + gb * 4, 1u);

  const int* __restrict__ idxp = lstm ? P.ivo : P.ivu;
  const int arow_off = (jt * 32 + (lane & 31)) * WSTR + half * 8;
  const int brow_off = bl * HS + half * 8;

  for (int t = 0; t <= S_LEN; ++t) {
    // ---- one-hop barrier: wave 0 polls all 32 group slots ----
    if (wave == 0) {
      const unsigned want = (unsigned)(t + 1);
      const unsigned* slot = arr + (lane & 31) * 4;
      while (!__all(AT_LOADU(slot) >= want)) { }
    }
    __syncthreads();

    const bool active = (layer == 0) ? (t < S_LEN) : (t >= 1);
    if (active) {
      const int cur = t & 1, prv = (t + 1) & 1;

      // ---- stage x_t into LDS [b][516] bf16; deep explicit load batches ----
      if (layer == 0) {
        // low half: embedding gather (cached loads, independent)
        const int b = tid >> 2, q = tid & 3;
        const int row = idxp[b * S_LEN + t];
        const float* __restrict__ vr = P.VE + (size_t)row * 256 + q * 64;
        float4 ve[8];
        #pragma unroll
        for (int jj = 0; jj < 8; ++jj) ve[jj] = *(const float4*)(vr + jj * 8 + 0);
        float4 vo[8];
        #pragma unroll
        for (int jj = 0; jj < 8; ++jj) vo[jj] = *(const float4*)(vr + jj * 8 + 4);
        unsigned long long* drow = (unsigned long long*)&hstage[b * HS + q * 64];
        #pragma unroll
        for (int jj = 0; jj < 8; ++jj) {
          drow[jj * 2]     = packbf4(ve[jj]);
          drow[jj * 2 + 1] = packbf4(vo[jj]);
        }
        // high half: h0_{t-1} (16 loads in flight)
        const unsigned long long* s64 =
            (const unsigned long long*)(wsb + (size_t)(lstm * 2 + prv) * 32768);
        unsigned long long v[16];
        #pragma unroll
        for (int j = 0; j < 16; ++j) v[j] = AT_LOADU(s64 + tid + j * 256);
        #pragma unroll
        for (int j = 0; j < 16; ++j) {
          const int i = tid + j * 256, bb = i >> 6, kq = i & 63;
          *(unsigned long long*)&hstage[bb * HS + 256 + kq * 4] = v[j];
        }
      } else {
        const unsigned long long* lo =
            (const unsigned long long*)(wsb + (size_t)(lstm * 2 + prv) * 32768);   // y0_{t-1}
        const unsigned long long* hi =
            (const unsigned long long*)(wsb + 131072 + (size_t)(lstm * 2 + cur) * 32768); // h1_{t-2}
        unsigned long long v[32];                    // 32 loads in flight
        #pragma unroll
        for (int j = 0; j < 16; ++j) v[j]      = AT_LOADU(lo + tid + j * 256);
        #pragma unroll
        for (int j = 0; j < 16; ++j) v[16 + j] = AT_LOADU(hi + tid + j * 256);
        #pragma unroll
        for (int j = 0; j < 16; ++j) {
          const int i = tid + j * 256, bb = i >> 6, kq = i & 63;
          *(unsigned long long*)&hstage[bb * HS + kq * 4] = v[j];
        }
        #pragma unroll
        for (int j = 0; j < 16; ++j) {
          const int i = tid + j * 256, bb = i >> 6, kq = i & 63;
          *(unsigned long long*)&hstage[bb * HS + 256 + kq * 4] = v[16 + j];
        }
      }
      __syncthreads();

      // ---- MFMA chain: 32 x mfma_f32_32x32x16_bf16, A and B from LDS ----
      floatx16 acc;
      #pragma unroll
      for (int r = 0; r < 16; ++r) acc[r] = 0.f;
      #pragma unroll
      for (int s = 0; s < 32; ++s) {
        short8 a = *(const short8*)&Wlds[arow_off + s * 16];
        short8 b = *(const short8*)&hstage[brow_off + s * 16];
        acc = __builtin_amdgcn_mfma_f32_32x32x16_bf16(a, b, acc, 0, 0, 0);
      }
      #pragma unroll
      for (int r = 0; r < 16; ++r) {
        const int row = (r & 3) + 8 * (r >> 2) + 4 * half;   // C/D layout (m74/m101)
        gatebuf[(jt * 32 + row) * 64 + bl] = acc[r];
      }
      __syncthreads();

      // ---- activations: thread = (b, mq), 4 m each ----
      {
        const int b = tid & 63, mq = tid >> 6;
        unsigned long long hpack = 0ull;
        #pragma unroll
        for (int i = 0; i < 4; ++i) {
          const int m = mq * 4 + i;
          const float g0 = gatebuf[(0 * 16 + m) * 64 + b] + bias_l[0 * 16 + m];
          const float g1 = gatebuf[(1 * 16 + m) * 64 + b] + bias_l[1 * 16 + m];
          const float g2 = gatebuf[(2 * 16 + m) * 64 + b] + bias_l[2 * 16 + m];
          const float g3 = gatebuf[(3 * 16 + m) * 64 + b] + bias_l[3 * 16 + m];
          const float ig = 1.f / (1.f + __expf(-g0));
          const float fg = 1.f / (1.f + __expf(-g1));
          const float gg = tanhf(g2);
          const float og = 1.f / (1.f + __expf(-g3));
          const float c  = fg * cst[m * 64 + b] + ig * gg;
          cst[m * 64 + b] = c;
          hpack |= ((unsigned long long)f2bf(og * tanhf(c))) << (16 * i);
        }
        unsigned long long* hout = (layer == 0)
            ? (unsigned long long*)(wsb + (size_t)(lstm * 2 + cur) * 32768)
            : (unsigned long long*)(wsb + 131072 + (size_t)(lstm * 2 + prv) * 32768);
        AT_STORE(hout + b * 64 + wg * 4 + mq, hpack);
      }
    }
    if (t < S_LEN) {
      __syncthreads();                   // vmcnt(0) drain: h stores IF-visible
      if (tid == 0) AT_STORE(arr + gb * 4, (unsigned)(t + 2));
    }
  }
}

// head: 64 blocks (one per batch) x 64 threads
__global__ __launch_bounds__(64) void head_kernel(Params P) {
  __shared__ float enc[256];
  __shared__ float dec[NCAT];
  const int b = blockIdx.x, t = threadIdx.x;
  char* wsb = (char*)P.ws;
  const unsigned short* hvu = (const unsigned short*)(wsb + 131072 + 1 * 32768) + b * 256;
  const unsigned short* hvo = (const unsigned short*)(wsb + 131072 + 3 * 32768) + b * 256;

  for (int m = t; m < 256; m += 64) {
    float s = P.rob[m];
    for (int j = 0; j < NCAT; ++j) s = fmaf(P.lro[b * NCAT + j], P.roW[m * NCAT + j], s);
    enc[m] = fmaxf(s, 0.f);
  }
  __syncthreads();
  for (int n = 0; n < NCAT; ++n) {
    const float* __restrict__ wr = P.ruW + n * 768;
    float s = 0.f;
    for (int k = t; k < 256; k += 64) {
      s = fmaf(bf2f(hvu[k]), wr[k], s);
      s = fmaf(bf2f(hvo[k]), wr[256 + k], s);
      s = fmaf(enc[k],       wr[512 + k], s);
    }
    for (int off = 32; off; off >>= 1) s += __shfl_down(s, off, 64);
    if (t == 0) dec[n] = s + P.rub[n];
  }
  __syncthreads();
  if (t == 0) {
    float M = dec[0];
    for (int j = 1; j < NCAT; ++j) M = fmaxf(M, dec[j]);
    float Ssum = 0.f;
    for (int j = 0; j < NCAT; ++j) Ssum += expf(dec[j] - M);
    const float lse = M + logf(Ssum);
    float neg = 0.f, kl = 0.f;
    for (int j = 0; j < NCAT; ++j) {
      const float lp = dec[j] - lse;
      const float q  = P.lru[b * NCAT + j];
      neg -= q * lp;
      kl  += q * (logf(q) - lp);
    }
    P.out[b] = neg;
    atomicAdd(&P.out[64], kl * 1.4426950408889634f * (1.f / 64.f));
  }
}

extern "C" void kernel_launch(void* const* d_in, const int* in_sizes, int n_in,
                              void* d_out, int out_size, void* d_ws, size_t ws_size,
                              hipStream_t stream) {
  Params P;
  P.ivu = (const int*)d_in[0];
  P.ivo = (const int*)d_in[1];
  P.lro = (const float*)d_in[2];
  if (in_sizes[3] >= in_sizes[4]) { P.VE = (const float*)d_in[3]; P.lru = (const float*)d_in[4]; }
  else                            { P.VE = (const float*)d_in[4]; P.lru = (const float*)d_in[3]; }
  // inst: 0 = vu-L0, 1 = vo-L0, 2 = vu-L1, 3 = vo-L1
  P.W[0][0] = (const float*)d_in[5];  P.W[0][1] = (const float*)d_in[6];
  P.b0[0]   = (const float*)d_in[7];  P.b1[0]   = (const float*)d_in[8];
  P.W[2][0] = (const float*)d_in[9];  P.W[2][1] = (const float*)d_in[10];
  P.b0[2]   = (const float*)d_in[11]; P.b1[2]   = (const float*)d_in[12];
  P.W[1][0] = (const float*)d_in[13]; P.W[1][1] = (const float*)d_in[14];
  P.b0[1]   = (const float*)d_in[15]; P.b1[1]   = (const float*)d_in[16];
  P.W[3][0] = (const float*)d_in[17]; P.W[3][1] = (const float*)d_in[18];
  P.b0[3]   = (const float*)d_in[19]; P.b1[3]   = (const float*)d_in[20];
  P.roW = (const float*)d_in[21]; P.rob = (const float*)d_in[22];
  P.ruW = (const float*)d_in[23]; P.rub = (const float*)d_in[24];
  P.ws  = (float*)d_ws;
  P.out = (float*)d_out;

  unsigned* bar = (unsigned*)((char*)d_ws + 262144);
  init_k<<<1, 256, 0, stream>>>(bar, P.out);

  void* args[] = { &P };
  hipLaunchCooperativeKernel((void*)lstm_all, dim3(64), dim3(256), args, 0, stream);
  head_kernel<<<64, 64, 0, stream>>>(P);
}